// Round 3
// baseline (406.404 us; speedup 1.0000x reference)
//
#include <hip/hip_runtime.h>
#include <stdint.h>
#include <math.h>

typedef __attribute__((ext_vector_type(4))) int i32x4;

constexpr int D_DIM = 1280;   // embedding dim (lin1 K, lin2 N)
constexpr int H_DIM = 5120;   // mlp dim      (lin1 N, lin2 K)
constexpr int BM = 256, BN = 128, BKB = 128;  // tile: 256x128, K-step 128 bytes

__device__ __forceinline__ void gload_lds16(const void* g, void* l) {
  __builtin_amdgcn_global_load_lds(
      (const __attribute__((address_space(1))) void*)g,
      (__attribute__((address_space(3))) void*)l,
      16, 0, 0);
}

// branchless erf, Abramowitz-Stegun 7.1.26, |eps| <= 1.5e-7
__device__ __forceinline__ float gelu_fast(float h) {
  const float x = h * 0.70710678118f;
  const float ax = fabsf(x);
  const float t = __frcp_rn(__builtin_fmaf(0.3275911f, ax, 1.0f));
  float p = __builtin_fmaf(1.061405429f, t, -1.453152027f);
  p = __builtin_fmaf(p, t, 1.421413741f);
  p = __builtin_fmaf(p, t, -0.284496736f);
  p = __builtin_fmaf(p, t, 0.254829592f);
  p *= t;
  const float e = __expf(-x * x);
  const float erf_ax = __builtin_fmaf(-p, e, 1.0f);
  const float erf_x = copysignf(erf_ax, x);
  return 0.5f * h * (1.0f + erf_x);
}

// ---- pack int32 (sign-extended int8 values) -> int8 -------------------------
__global__ void __launch_bounds__(256) k_pack(const int* __restrict__ in,
                                              int8_t* __restrict__ out,
                                              long n) {
  long i = ((long)blockIdx.x * 256 + threadIdx.x) * 16;
  if (i >= n) return;
  const int* p = in + i;
  i32x4 a = *(const i32x4*)(p);
  i32x4 b = *(const i32x4*)(p + 4);
  i32x4 c = *(const i32x4*)(p + 8);
  i32x4 d = *(const i32x4*)(p + 12);
  i32x4 r;
  r.x = (a.x & 255) | ((a.y & 255) << 8) | ((a.z & 255) << 16) | (a.w << 24);
  r.y = (b.x & 255) | ((b.y & 255) << 8) | ((b.z & 255) << 16) | (b.w << 24);
  r.z = (c.x & 255) | ((c.y & 255) << 8) | ((c.z & 255) << 16) | (c.w << 24);
  r.w = (d.x & 255) | ((d.y & 255) << 8) | ((d.z & 255) << 16) | (d.w << 24);
  *(i32x4*)(out + i) = r;
}

// ---- fused int8 GEMM, 3-buffer LDS ring, counted vmcnt, T2 swizzle ----------
// A [Mtiles*256, KDIM] i8 row-major; B [NDIM, KDIM] i8 row-major (NT GEMM).
// GELU=true: C = requant(gelu(acc*s1 + bias))   -> int8  [ld NDIM]
// GELU=false: C = acc*s1 + bias                 -> fp32  [ld NDIM]
template <int KDIM, int NDIM, bool GELU>
__global__ void __launch_bounds__(512, 2)
k_gemm(const int8_t* __restrict__ A, const int8_t* __restrict__ B,
       const float* __restrict__ bias, const float* __restrict__ ps1,
       const float* __restrict__ ps2, void* __restrict__ Cout, int Mtiles) {
  constexpr int NT = KDIM / BKB;        // K-tiles (10 or 40)
  constexpr int BNCNT = NDIM / BN;      // 40 or 10
  constexpr int G = BNCNT * 4;          // 4-row supertile group

  __shared__ __align__(16) int8_t As[3][BM * BKB];  // 3 x 32 KB
  __shared__ __align__(16) int8_t Bs[3][BN * BKB];  // 3 x 16 KB

  // ---- block mapping: bijective XCD chunk + 4-row grouping ------------------
  const int nwg = Mtiles * BNCNT;
  int bm, bn;
  {
    const int bid = blockIdx.x;
    const int q = nwg >> 3, r = nwg & 7, x = bid & 7, l = bid >> 3;
    const int swz = (x < r ? x * (q + 1) : r * (q + 1) + (x - r) * q) + l;
    if ((Mtiles & 3) == 0) {
      const int g = swz / G, rr = swz % G;
      bn = rr >> 2;
      bm = g * 4 + (rr & 3);
    } else {
      bn = swz % BNCNT;
      bm = swz / BNCNT;
    }
  }

  const int tid = threadIdx.x;
  const int lane = tid & 63, wid = tid >> 6;
  const int wr = wid >> 1, wc = wid & 1;   // 4 M-waves x 2 N-waves, 64x64 each

  // ---- staging setup (linear LDS dest, inverse-swizzled global src) ---------
  const int srow = tid >> 3;                                  // 0..63
  const int kswz = (((tid & 7) ^ (srow & 7)) << 4);           // src koff in row
  const int8_t* srcA = A + (size_t)(bm * BM + srow) * KDIM + kswz;
  const int8_t* srcB = B + (size_t)(bn * BN + srow) * KDIM + kswz;
  const int dT = tid * 16;

  // ---- fragment ds_read offsets (swizzled) ----------------------------------
  const int r0 = lane & 15, kq = (lane >> 4) << 4;
  const int fsw = (r0 & 7) << 4;
  int offA[4][2], offB[4][2];
#pragma unroll
  for (int m = 0; m < 4; ++m)
#pragma unroll
    for (int j = 0; j < 2; ++j)
      offA[m][j] = (wr * 64 + m * 16 + r0) * BKB + ((j * 64 + kq) ^ fsw);
#pragma unroll
  for (int n = 0; n < 4; ++n)
#pragma unroll
    for (int j = 0; j < 2; ++j)
      offB[n][j] = (wc * 64 + n * 16 + r0) * BKB + ((j * 64 + kq) ^ fsw);

  i32x4 acc[4][4] = {};

  auto STAGE = [&](int buf) {   // 6 gload_lds per wave (A:4, B:2)
#pragma unroll
    for (int p = 0; p < 4; ++p)
      gload_lds16(srcA + (size_t)p * 64 * KDIM, &As[buf][dT + p * 8192]);
#pragma unroll
    for (int p = 0; p < 2; ++p)
      gload_lds16(srcB + (size_t)p * 64 * KDIM, &Bs[buf][dT + p * 8192]);
    srcA += BKB;
    srcB += BKB;
  };

  auto COMPUTE = [&](int buf) {
#pragma unroll
    for (int j = 0; j < 2; ++j) {
      i32x4 af[4], bf[4];
#pragma unroll
      for (int m = 0; m < 4; ++m) af[m] = *(const i32x4*)&As[buf][offA[m][j]];
#pragma unroll
      for (int n = 0; n < 4; ++n) bf[n] = *(const i32x4*)&Bs[buf][offB[n][j]];
      __builtin_amdgcn_s_setprio(1);
#pragma unroll
      for (int m = 0; m < 4; ++m)
#pragma unroll
        for (int n = 0; n < 4; ++n)
          acc[m][n] =
              __builtin_amdgcn_mfma_i32_16x16x64_i8(af[m], bf[n], acc[m][n], 0, 0, 0);
      __builtin_amdgcn_s_setprio(0);
    }
  };

  // ---- prologue: tiles 0,1 in flight ----------------------------------------
  STAGE(0);
  STAGE(1);
  asm volatile("s_waitcnt vmcnt(6)" ::: "memory");  // tile 0 landed (own slice)
  __builtin_amdgcn_s_barrier();                     // -> all waves' slices
  __builtin_amdgcn_sched_barrier(0);

  // ---- main loop: 1 barrier per K-tile, vmcnt never 0 mid-loop --------------
  int cur = 0;
#pragma unroll 1
  for (int t = 0; t < NT; ++t) {
    if (t + 2 < NT) {
      const int nxt2 = cur + 2 >= 3 ? cur - 1 : cur + 2;
      STAGE(nxt2);  // writes buffer freed at previous barrier: race-free
    }
    COMPUTE(cur);
    if (t + 2 < NT) {
      asm volatile("s_waitcnt vmcnt(6)" ::: "memory");  // tile t+1 landed
    } else if (t + 1 < NT) {
      asm volatile("s_waitcnt vmcnt(0)" ::: "memory");  // epilogue drain
    }
    if (t + 1 < NT) {
      __builtin_amdgcn_s_barrier();
      __builtin_amdgcn_sched_barrier(0);
    }
    cur = cur + 1 >= 3 ? 0 : cur + 1;
  }

  // ---- epilogue -------------------------------------------------------------
  // C/D 16x16 layout: col = lane&15, row = (lane>>4)*4 + reg
  const int rowb = bm * BM + wr * 64 + ((lane >> 4) << 2);
  const int colb = bn * BN + wc * 64 + r0;
  if constexpr (GELU) {
    const float s1 = *ps1;
    const float rs = 1.0f / (*ps2);
    int8_t* Q = (int8_t*)Cout;
#pragma unroll
    for (int n = 0; n < 4; ++n) {
      const int col = colb + n * 16;
      const float bv = bias[col];
#pragma unroll
      for (int m = 0; m < 4; ++m) {
#pragma unroll
        for (int r = 0; r < 4; ++r) {
          const int row = rowb + m * 16 + r;
          const float h = __builtin_fmaf((float)acc[m][n][r], s1, bv);
          float qf = rintf(gelu_fast(h) * rs);
          qf = fminf(127.0f, fmaxf(-128.0f, qf));
          Q[(size_t)row * NDIM + col] = (int8_t)(int)qf;
        }
      }
    }
  } else {
    const float s1 = *ps1;
    float* O = (float*)Cout;
#pragma unroll
    for (int n = 0; n < 4; ++n) {
      const int col = colb + n * 16;
      const float bv = bias[col];
#pragma unroll
      for (int m = 0; m < 4; ++m) {
#pragma unroll
        for (int r = 0; r < 4; ++r) {
          const int row = rowb + m * 16 + r;
          O[(size_t)row * NDIM + col] = __builtin_fmaf((float)acc[m][n][r], s1, bv);
        }
      }
    }
  }
}

extern "C" void kernel_launch(void* const* d_in, const int* in_sizes, int n_in,
                              void* d_out, int out_size, void* d_ws, size_t ws_size,
                              hipStream_t stream) {
  (void)in_sizes; (void)n_in; (void)out_size;
  const int*   x32  = (const int*)d_in[0];
  const int*   w132 = (const int*)d_in[1];
  const float* b1   = (const float*)d_in[2];
  const int*   w232 = (const int*)d_in[3];
  const float* b2   = (const float*)d_in[4];
  const float* a1   = (const float*)d_in[5];
  const float* sreq = (const float*)d_in[6];
  const float* a2   = (const float*)d_in[7];
  float* out = (float*)d_out;

  const int M = 4 * 4096;                       // 16384 tokens
  const size_t WN = (size_t)H_DIM * D_DIM;      // 6,553,600 weights each

  int8_t* w1p  = (int8_t*)d_ws;
  int8_t* w2p  = w1p + WN;
  int8_t* base = w2p + WN;

  // chunk M (multiple of 256) so packed-x chunk + q chunk fit in workspace
  size_t avail = ws_size > 2 * WN ? ws_size - 2 * WN : 0;
  size_t rows = avail / (size_t)(D_DIM + H_DIM);
  int Mc = (int)((rows / BM) * BM);
  if (Mc > M) Mc = M;
  if (Mc < BM) Mc = BM;

  k_pack<<<(int)(WN / 4096), 256, 0, stream>>>(w132, w1p, (long)WN);
  k_pack<<<(int)(WN / 4096), 256, 0, stream>>>(w232, w2p, (long)WN);

  for (int m0 = 0; m0 < M; m0 += Mc) {
    const int mc = (M - m0 < Mc) ? (M - m0) : Mc;
    int8_t* xp = base;
    int8_t* q  = base + (size_t)Mc * D_DIM;
    const size_t nx = (size_t)mc * D_DIM;
    const int mt = mc / BM;
    k_pack<<<(int)(nx / 4096), 256, 0, stream>>>(x32 + (size_t)m0 * D_DIM, xp, (long)nx);
    k_gemm<D_DIM, H_DIM, true><<<mt * (H_DIM / BN), 512, 0, stream>>>(
        xp, w1p, b1, a1, sreq, q, mt);
    k_gemm<H_DIM, D_DIM, false><<<mt * (D_DIM / BN), 512, 0, stream>>>(
        q, w2p, b2, a2, nullptr, out + (size_t)m0 * D_DIM, mt);
  }
}

// Round 4
// 380.455 us; speedup vs baseline: 1.0682x; 1.0682x over previous
//
#include <hip/hip_runtime.h>
#include <stdint.h>
#include <math.h>

typedef __attribute__((ext_vector_type(4))) int i32x4;

constexpr int D_DIM = 1280;   // embedding dim (lin1 K, lin2 N)
constexpr int H_DIM = 5120;   // mlp dim      (lin1 N, lin2 K)

__device__ __forceinline__ void gload_lds16(const void* g, void* l) {
  __builtin_amdgcn_global_load_lds(
      (const __attribute__((address_space(1))) void*)g,
      (__attribute__((address_space(3))) void*)l,
      16, 0, 0);
}

// branchless erf, Abramowitz-Stegun 7.1.26, |eps| <= 1.5e-7
__device__ __forceinline__ float gelu_fast(float h) {
  const float x = h * 0.70710678118f;
  const float ax = fabsf(x);
  const float t = __frcp_rn(__builtin_fmaf(0.3275911f, ax, 1.0f));
  float p = __builtin_fmaf(1.061405429f, t, -1.453152027f);
  p = __builtin_fmaf(p, t, 1.421413741f);
  p = __builtin_fmaf(p, t, -0.284496736f);
  p = __builtin_fmaf(p, t, 0.254829592f);
  p *= t;
  const float e = __expf(-x * x);
  const float erf_ax = __builtin_fmaf(-p, e, 1.0f);
  const float erf_x = copysignf(erf_ax, x);
  return 0.5f * h * (1.0f + erf_x);
}

// ---- pack int32 (sign-extended int8 values) -> int8 -------------------------
__global__ void __launch_bounds__(256) k_pack(const int* __restrict__ in,
                                              int8_t* __restrict__ out,
                                              long n) {
  long i = ((long)blockIdx.x * 256 + threadIdx.x) * 16;
  if (i >= n) return;
  const int* p = in + i;
  i32x4 a = *(const i32x4*)(p);
  i32x4 b = *(const i32x4*)(p + 4);
  i32x4 c = *(const i32x4*)(p + 8);
  i32x4 d = *(const i32x4*)(p + 12);
  i32x4 r;
  r.x = (a.x & 255) | ((a.y & 255) << 8) | ((a.z & 255) << 16) | (a.w << 24);
  r.y = (b.x & 255) | ((b.y & 255) << 8) | ((b.z & 255) << 16) | (b.w << 24);
  r.z = (c.x & 255) | ((c.y & 255) << 8) | ((c.z & 255) << 16) | (c.w << 24);
  r.w = (d.x & 255) | ((d.y & 255) << 8) | ((d.z & 255) << 16) | (d.w << 24);
  *(i32x4*)(out + i) = r;
}

// ---- frag-load + MFMA phase macros (static indices everywhere) --------------
#define FRAG_LOADS(QM)                                                        \
  i32x4 af[2][2], bf[4][2];                                                   \
  _Pragma("unroll") for (int m = 0; m < 2; ++m) {                             \
    af[m][0] = *(const i32x4*)(Ac + rowA0 + (QM)*4096 + m * 2048 + kof0);     \
    af[m][1] = *(const i32x4*)(Ac + rowA0 + (QM)*4096 + m * 2048 + kof1);     \
  }                                                                           \
  _Pragma("unroll") for (int n = 0; n < 4; ++n) {                             \
    bf[n][0] = *(const i32x4*)(Bc + rowB0 + n * 2048 + kof0);                 \
    bf[n][1] = *(const i32x4*)(Bc + rowB0 + n * 2048 + kof1);                 \
  }

#define MFMA_CLUSTER(QM)                                                      \
  __builtin_amdgcn_s_setprio(1);                                              \
  _Pragma("unroll") for (int kk = 0; kk < 2; ++kk)                            \
      _Pragma("unroll") for (int m = 0; m < 2; ++m)                           \
          _Pragma("unroll") for (int n = 0; n < 4; ++n)                       \
              acc[(QM)*2 + m][n] = __builtin_amdgcn_mfma_i32_16x16x64_i8(     \
                  af[m][kk], bf[n][kk], acc[(QM)*2 + m][n], 0, 0, 0);         \
  __builtin_amdgcn_s_setprio(0);

// ---- fused int8 GEMM: 256x128 tile, 3-K-tile LDS ring, 2 phases/tile -------
// A [Mtiles*256, KDIM] i8 row-major; B [NDIM, KDIM] i8 row-major (NT GEMM).
// GELU=true: int8 out (requant(gelu(...))); GELU=false: fp32 out.
template <int KDIM, int NDIM, bool GELU>
__global__ void __launch_bounds__(512, 2)
k_gemm(const int8_t* __restrict__ A, const int8_t* __restrict__ B,
       const float* __restrict__ bias, const float* __restrict__ ps1,
       const float* __restrict__ ps2, void* __restrict__ Cout, int Mtiles) {
  constexpr int BM = 256, BN = 128, BKB = 128;
  constexpr int NT = KDIM / BKB;        // 10 (lin1) / 40 (lin2)
  constexpr int BNC = NDIM / BN;        // 40 / 10
  constexpr int G = BNC * 4;

  __shared__ __align__(16) int8_t As[3][BM * BKB];  // 3 x 32 KB
  __shared__ __align__(16) int8_t Bs[3][BN * BKB];  // 3 x 16 KB

  // ---- block mapping: bijective XCD chunk + 4-row grouping ------------------
  const int nwg = Mtiles * BNC;
  int bm, bn;
  {
    const int bid = blockIdx.x;
    const int q = nwg >> 3, r = nwg & 7, x = bid & 7, l = bid >> 3;
    const int swz = (x < r ? x * (q + 1) : r * (q + 1) + (x - r) * q) + l;
    if ((Mtiles & 3) == 0) {
      const int g = swz / G, rr = swz % G;
      bn = rr >> 2;
      bm = g * 4 + (rr & 3);
    } else {
      bn = swz % BNC;
      bm = swz / BNC;
    }
  }

  const int tid = threadIdx.x;
  const int lane = tid & 63, wid = tid >> 6;
  const int wr = wid >> 1, wc = wid & 1;  // 4 M-waves x 2 N-waves, 64x64 each

  // ---- staging: linear LDS dest, inverse-swizzled global source -------------
  const int srow = tid >> 3;                          // 0..63
  const int soff = (((tid & 7) ^ (srow & 7)) << 4);   // pre-swizzled k-slot
  const int8_t* Ath = A + (size_t)(bm * BM + srow) * KDIM + soff;
  const int8_t* Bth = B + (size_t)(bn * BN + srow) * KDIM + soff;
  const int dA = tid * 16;

  auto STAGE_A = [&](int buf, int tt, int u) {  // A half u: rows u*128..+128
    const int8_t* g = Ath + (size_t)(u * 128) * KDIM + tt * BKB;
    gload_lds16(g, &As[buf][u * 16384 + dA]);
    gload_lds16(g + (size_t)64 * KDIM, &As[buf][u * 16384 + dA + 8192]);
  };
  auto STAGE_B = [&](int buf, int tt) {
    const int8_t* g = Bth + tt * BKB;
    gload_lds16(g, &Bs[buf][dA]);
    gload_lds16(g + (size_t)64 * KDIM, &Bs[buf][dA + 8192]);
  };

  // ---- fragment ds_read offsets (swizzled, conflict-free: r3-verified) ------
  const int r0 = lane & 15, kq = (lane >> 4) << 4;
  const int fsw = (r0 & 7) << 4;
  const int kof0 = kq ^ fsw;
  const int kof1 = (64 + kq) ^ fsw;
  const int rowA0 = (wr * 64 + r0) * BKB;
  const int rowB0 = (wc * 64 + r0) * BKB;

  i32x4 acc[4][4] = {};

  // ---- prologue: tiles 0 and 1 fully issued (6 loads each, in order) --------
  STAGE_A(0, 0, 0); STAGE_A(0, 0, 1); STAGE_B(0, 0);
  STAGE_A(1, 1, 0); STAGE_A(1, 1, 1); STAGE_B(1, 1);
  asm volatile("s_waitcnt vmcnt(6)" ::: "memory");  // tile 0 landed
  __builtin_amdgcn_s_barrier();
  __builtin_amdgcn_sched_barrier(0);

  // ---- main loop: 2 phases per K-tile, stage 2 tiles ahead ------------------
  int cur = 0;
#pragma unroll 1
  for (int t = 0; t < NT; ++t) {
    const int nxt2 = cur ? cur - 1 : 2;   // (cur+2)%3: freed at t-1's end
    const bool st = (t + 2 < NT);
    const int8_t* Ac = As[cur];
    const int8_t* Bc = Bs[cur];
    {  // phase 0: M-half 0 of wave tile; stage A halves of tile t+2
      FRAG_LOADS(0)
      if (st) { STAGE_A(nxt2, t + 2, 0); STAGE_A(nxt2, t + 2, 1); }
      __builtin_amdgcn_s_barrier();
      asm volatile("s_waitcnt lgkmcnt(0)" ::: "memory");
      __builtin_amdgcn_sched_barrier(0);
      MFMA_CLUSTER(0)
      __builtin_amdgcn_s_barrier();
    }
    {  // phase 1: M-half 1; stage B of tile t+2; tile-boundary wait
      FRAG_LOADS(1)
      if (st) STAGE_B(nxt2, t + 2);
      __builtin_amdgcn_s_barrier();
      asm volatile("s_waitcnt lgkmcnt(0)" ::: "memory");
      __builtin_amdgcn_sched_barrier(0);
      MFMA_CLUSTER(1)
      if (st)
        asm volatile("s_waitcnt vmcnt(6)" ::: "memory");   // tile t+1 landed
      else if (t + 1 < NT)
        asm volatile("s_waitcnt vmcnt(0)" ::: "memory");   // epilogue drain
      if (t + 1 < NT) {
        __builtin_amdgcn_s_barrier();
        __builtin_amdgcn_sched_barrier(0);
      }
    }
    cur = cur + 1 >= 3 ? 0 : cur + 1;
  }

  // ---- epilogue: C/D 16x16 layout col = lane&15, row = (lane>>4)*4 + reg ----
  const int rowb = bm * BM + wr * 64 + ((lane >> 4) << 2);
  const int colb = bn * BN + wc * 64 + r0;
  if constexpr (GELU) {
    const float s1 = *ps1;
    const float rs = 1.0f / (*ps2);
    int8_t* Q = (int8_t*)Cout;
#pragma unroll
    for (int n = 0; n < 4; ++n) {
      const int col = colb + n * 16;
      const float bv = bias[col];
#pragma unroll
      for (int m = 0; m < 4; ++m) {
#pragma unroll
        for (int r = 0; r < 4; ++r) {
          const int row = rowb + m * 16 + r;
          const float h = __builtin_fmaf((float)acc[m][n][r], s1, bv);
          float qf = rintf(gelu_fast(h) * rs);
          qf = fminf(127.0f, fmaxf(-128.0f, qf));
          Q[(size_t)row * NDIM + col] = (int8_t)(int)qf;
        }
      }
    }
  } else {
    const float s1 = *ps1;
    float* O = (float*)Cout;
#pragma unroll
    for (int n = 0; n < 4; ++n) {
      const int col = colb + n * 16;
      const float bv = bias[col];
#pragma unroll
      for (int m = 0; m < 4; ++m) {
#pragma unroll
        for (int r = 0; r < 4; ++r) {
          const int row = rowb + m * 16 + r;
          O[(size_t)row * NDIM + col] = __builtin_fmaf((float)acc[m][n][r], s1, bv);
        }
      }
    }
  }
}

extern "C" void kernel_launch(void* const* d_in, const int* in_sizes, int n_in,
                              void* d_out, int out_size, void* d_ws, size_t ws_size,
                              hipStream_t stream) {
  (void)in_sizes; (void)n_in; (void)out_size;
  const int*   x32  = (const int*)d_in[0];
  const int*   w132 = (const int*)d_in[1];
  const float* b1   = (const float*)d_in[2];
  const int*   w232 = (const int*)d_in[3];
  const float* b2   = (const float*)d_in[4];
  const float* a1   = (const float*)d_in[5];
  const float* sreq = (const float*)d_in[6];
  const float* a2   = (const float*)d_in[7];
  float* out = (float*)d_out;

  const int M = 4 * 4096;                       // 16384 tokens
  const size_t WN = (size_t)H_DIM * D_DIM;      // 6,553,600 weights each
  constexpr int BM = 256, BN = 128;

  int8_t* w1p  = (int8_t*)d_ws;
  int8_t* w2p  = w1p + WN;
  int8_t* base = w2p + WN;

  // chunk M (multiple of 256) so packed-x chunk + q chunk fit in workspace
  size_t avail = ws_size > 2 * WN ? ws_size - 2 * WN : 0;
  size_t rows = avail / (size_t)(D_DIM + H_DIM);
  int Mc = (int)((rows / BM) * BM);
  if (Mc > M) Mc = M;
  if (Mc < BM) Mc = BM;

  k_pack<<<(int)(WN / 4096), 256, 0, stream>>>(w132, w1p, (long)WN);
  k_pack<<<(int)(WN / 4096), 256, 0, stream>>>(w232, w2p, (long)WN);

  for (int m0 = 0; m0 < M; m0 += Mc) {
    const int mc = (M - m0 < Mc) ? (M - m0) : Mc;
    int8_t* xp = base;
    int8_t* q  = base + (size_t)Mc * D_DIM;
    const size_t nx = (size_t)mc * D_DIM;
    const int mt = mc / BM;
    k_pack<<<(int)(nx / 4096), 256, 0, stream>>>(x32 + (size_t)m0 * D_DIM, xp, (long)nx);
    k_gemm<D_DIM, H_DIM, true><<<mt * (H_DIM / BN), 512, 0, stream>>>(
        xp, w1p, b1, a1, sreq, q, mt);
    k_gemm<H_DIM, D_DIM, false><<<mt * (D_DIM / BN), 512, 0, stream>>>(
        q, w2p, b2, a2, nullptr, out + (size_t)m0 * D_DIM, mt);
  }
}

// Round 5
// 333.417 us; speedup vs baseline: 1.2189x; 1.1411x over previous
//
#include <hip/hip_runtime.h>
#include <stdint.h>
#include <math.h>

typedef __attribute__((ext_vector_type(4))) int i32x4;
typedef __attribute__((ext_vector_type(4))) float f32x4;

constexpr int D_DIM = 1280;   // embedding dim (lin1 K, lin2 N)
constexpr int H_DIM = 5120;   // mlp dim      (lin1 N, lin2 K)

__device__ __forceinline__ void gload_lds16(const void* g, void* l) {
  __builtin_amdgcn_global_load_lds(
      (const __attribute__((address_space(1))) void*)g,
      (__attribute__((address_space(3))) void*)l,
      16, 0, 0);
}

// branchless erf, Abramowitz-Stegun 7.1.26, |eps| <= 1.5e-7
__device__ __forceinline__ float gelu_fast(float h) {
  const float x = h * 0.70710678118f;
  const float ax = fabsf(x);
  const float t = __frcp_rn(__builtin_fmaf(0.3275911f, ax, 1.0f));
  float p = __builtin_fmaf(1.061405429f, t, -1.453152027f);
  p = __builtin_fmaf(p, t, 1.421413741f);
  p = __builtin_fmaf(p, t, -0.284496736f);
  p = __builtin_fmaf(p, t, 0.254829592f);
  p *= t;
  const float e = __expf(-x * x);
  const float erf_ax = __builtin_fmaf(-p, e, 1.0f);
  const float erf_x = copysignf(erf_ax, x);
  return 0.5f * h * (1.0f + erf_x);
}

// ---- pack int32 (sign-extended int8) -> int8; two sources fused -------------
__global__ void __launch_bounds__(256) k_packw(const int* __restrict__ s1,
                                               const int* __restrict__ s2,
                                               int8_t* __restrict__ out,
                                               long wn) {
  long i = ((long)blockIdx.x * 256 + threadIdx.x) * 16;
  const int* p = (i < wn) ? (s1 + i) : (s2 + (i - wn));
  i32x4 a = *(const i32x4*)(p);
  i32x4 b = *(const i32x4*)(p + 4);
  i32x4 c = *(const i32x4*)(p + 8);
  i32x4 d = *(const i32x4*)(p + 12);
  i32x4 r;
  r.x = (a.x & 255) | ((a.y & 255) << 8) | ((a.z & 255) << 16) | (a.w << 24);
  r.y = (b.x & 255) | ((b.y & 255) << 8) | ((b.z & 255) << 16) | (b.w << 24);
  r.z = (c.x & 255) | ((c.y & 255) << 8) | ((c.z & 255) << 16) | (c.w << 24);
  r.w = (d.x & 255) | ((d.y & 255) << 8) | ((d.z & 255) << 16) | (d.w << 24);
  *(i32x4*)(out + i) = r;
}

__global__ void __launch_bounds__(256) k_pack(const int* __restrict__ in,
                                              int8_t* __restrict__ out,
                                              long n) {
  long i = ((long)blockIdx.x * 256 + threadIdx.x) * 16;
  if (i >= n) return;
  const int* p = in + i;
  i32x4 a = *(const i32x4*)(p);
  i32x4 b = *(const i32x4*)(p + 4);
  i32x4 c = *(const i32x4*)(p + 8);
  i32x4 d = *(const i32x4*)(p + 12);
  i32x4 r;
  r.x = (a.x & 255) | ((a.y & 255) << 8) | ((a.z & 255) << 16) | (a.w << 24);
  r.y = (b.x & 255) | ((b.y & 255) << 8) | ((b.z & 255) << 16) | (b.w << 24);
  r.z = (c.x & 255) | ((c.y & 255) << 8) | ((c.z & 255) << 16) | (c.w << 24);
  r.w = (d.x & 255) | ((d.y & 255) << 8) | ((d.z & 255) << 16) | (d.w << 24);
  *(i32x4*)(out + i) = r;
}

// ---- fused int8 GEMM: 128x128 tile, BK=128, 2-phase LDS dbuf, 4 waves -------
// A [Mt*128, KDIM] i8 row-major; B [NDIM, KDIM] i8 row-major (NT GEMM).
// GELU=true : acc computed TRANSPOSED (mfma(b,a)); per-lane 4 consecutive h ->
//             requant + pack 4 int8 -> one dword store. int8 out [ld NDIM].
// GELU=false: fp32 out = acc*s1 + bias, coalesced f32 stores.
template <int KDIM, int NDIM, bool GELU>
__global__ void __launch_bounds__(256, 2)
k_gemm(const int8_t* __restrict__ A, const int8_t* __restrict__ B,
       const float* __restrict__ bias, const float* __restrict__ ps1,
       const float* __restrict__ ps2, void* __restrict__ Cout, int Mtiles) {
  constexpr int BM = 128, BN = 128, BKB = 128;
  constexpr int NT = KDIM / BKB;   // 10 (lin1) / 40 (lin2)
  constexpr int BNC = NDIM / BN;   // 40 / 10
  constexpr int G = BNC * 4;

  __shared__ __align__(16) int8_t As[2][BM * BKB];  // 2 x 16 KB
  __shared__ __align__(16) int8_t Bs[2][BN * BKB];  // 2 x 16 KB

  // ---- block mapping: bijective XCD chunk + 4-row grouping (r4-verified) ----
  const int nwg = Mtiles * BNC;
  int bm, bn;
  {
    const int bid = blockIdx.x;
    const int q = nwg >> 3, r = nwg & 7, x = bid & 7, l = bid >> 3;
    const int swz = (x < r ? x * (q + 1) : r * (q + 1) + (x - r) * q) + l;
    if ((Mtiles & 3) == 0) {
      const int g = swz / G, rr = swz % G;
      bn = rr >> 2;
      bm = g * 4 + (rr & 3);
    } else {
      bn = swz % BNC;
      bm = swz / BNC;
    }
  }

  const int tid = threadIdx.x;
  const int lane = tid & 63, wid = tid >> 6;
  const int wr = wid >> 1, wc = wid & 1;  // 2x2 waves, 64x64 out each

  // ---- staging: linear LDS dest, inverse-swizzled global source -------------
  // thread stages rows {tid>>3 + 32p}; in-row 16B slot = (tid&7) ^ (row&7)
  const int srow = tid >> 3;                          // 0..31
  const int soff = (((tid & 7) ^ (srow & 7)) << 4);
  const int8_t* Ath = A + (size_t)(bm * BM + srow) * KDIM + soff;
  const int8_t* Bth = B + (size_t)(bn * BN + srow) * KDIM + soff;
  const int dT = tid * 16;

  auto STAGE = [&](int buf, int t) {
    const int8_t* ga = Ath + t * BKB;
    const int8_t* gb = Bth + t * BKB;
#pragma unroll
    for (int p = 0; p < 4; ++p)
      gload_lds16(ga + (size_t)(p * 32) * KDIM, &As[buf][dT + p * 4096]);
#pragma unroll
    for (int p = 0; p < 4; ++p)
      gload_lds16(gb + (size_t)(p * 32) * KDIM, &Bs[buf][dT + p * 4096]);
  };

  // ---- fragment ds_read offsets (swizzled; zero-conflict per r3/r4) ---------
  const int r0 = lane & 15, kq = (lane >> 4) << 4;
  const int fsw = (r0 & 7) << 4;
  const int kof0 = kq ^ fsw;
  const int kof1 = (64 + kq) ^ fsw;
  const int rowA0 = (wr * 64 + r0) * BKB;
  const int rowB0 = (wc * 64 + r0) * BKB;

  i32x4 acc[4][4] = {};

  auto COMPUTE = [&](int buf) {
    const int8_t* Ac = As[buf];
    const int8_t* Bc = Bs[buf];
#pragma unroll
    for (int j = 0; j < 2; ++j) {
      const int kof = j ? kof1 : kof0;
      i32x4 af[4], bf[4];
#pragma unroll
      for (int m = 0; m < 4; ++m) af[m] = *(const i32x4*)(Ac + rowA0 + m * 2048 + kof);
#pragma unroll
      for (int n = 0; n < 4; ++n) bf[n] = *(const i32x4*)(Bc + rowB0 + n * 2048 + kof);
      if constexpr (GELU) {
        // transposed: acc[n][m]; D-row = h (B side), D-col = token (A side)
#pragma unroll
        for (int n = 0; n < 4; ++n)
#pragma unroll
          for (int m = 0; m < 4; ++m)
            acc[n][m] =
                __builtin_amdgcn_mfma_i32_16x16x64_i8(bf[n], af[m], acc[n][m], 0, 0, 0);
      } else {
#pragma unroll
        for (int m = 0; m < 4; ++m)
#pragma unroll
          for (int n = 0; n < 4; ++n)
            acc[m][n] =
                __builtin_amdgcn_mfma_i32_16x16x64_i8(af[m], bf[n], acc[m][n], 0, 0, 0);
      }
    }
  };

  // ---- 2-phase loop: stage t+1 under compute t, one barrier per tile --------
  STAGE(0, 0);
  __syncthreads();
#pragma unroll 1
  for (int t = 0; t < NT; ++t) {
    const int cur = t & 1;
    if (t + 1 < NT) STAGE(cur ^ 1, t + 1);
    COMPUTE(cur);
    __syncthreads();   // drains vmcnt(0)+lgkmcnt(0): tile t+1 landed, t reads done
  }

  // ---- epilogue -------------------------------------------------------------
  const int hq = lane >> 4;
  if constexpr (GELU) {
    // acc[n][m][r]: h = bn*128 + wc*64 + n*16 + hq*4 + r  (4 consecutive h)
    //              token = bm*128 + wr*64 + m*16 + r0
    const float s1 = *ps1;
    const float rs = 1.0f / (*ps2);
    int8_t* Q = (int8_t*)Cout;
    const int hb0 = bn * BN + wc * 64 + hq * 4;
    const int tok0 = bm * BM + wr * 64 + r0;
#pragma unroll
    for (int n = 0; n < 4; ++n) {
      const int hb = hb0 + n * 16;
      const f32x4 bv = *(const f32x4*)(bias + hb);
#pragma unroll
      for (int m = 0; m < 4; ++m) {
        const int tok = tok0 + m * 16;
        uint32_t pk = 0;
#pragma unroll
        for (int r = 0; r < 4; ++r) {
          const float h = __builtin_fmaf((float)acc[n][m][r], s1, bv[r]);
          float qf = rintf(gelu_fast(h) * rs);
          qf = fminf(127.0f, fmaxf(-128.0f, qf));
          pk |= ((uint32_t)((int)qf & 255)) << (r * 8);
        }
        *(uint32_t*)(Q + (size_t)tok * NDIM + hb) = pk;
      }
    }
  } else {
    // acc[m][n][r]: row = token = bm*128 + wr*64 + m*16 + hq*4 + r
    //              col = d     = bn*128 + wc*64 + n*16 + r0
    const float s1 = *ps1;
    float* O = (float*)Cout;
    const int rowb = bm * BM + wr * 64 + hq * 4;
    const int colb = bn * BN + wc * 64 + r0;
#pragma unroll
    for (int n = 0; n < 4; ++n) {
      const int col = colb + n * 16;
      const float bv = bias[col];
#pragma unroll
      for (int m = 0; m < 4; ++m) {
#pragma unroll
        for (int r = 0; r < 4; ++r) {
          const int row = rowb + m * 16 + r;
          O[(size_t)row * NDIM + col] = __builtin_fmaf((float)acc[m][n][r], s1, bv);
        }
      }
    }
  }
}

extern "C" void kernel_launch(void* const* d_in, const int* in_sizes, int n_in,
                              void* d_out, int out_size, void* d_ws, size_t ws_size,
                              hipStream_t stream) {
  (void)in_sizes; (void)n_in; (void)out_size;
  const int*   x32  = (const int*)d_in[0];
  const int*   w132 = (const int*)d_in[1];
  const float* b1   = (const float*)d_in[2];
  const int*   w232 = (const int*)d_in[3];
  const float* b2   = (const float*)d_in[4];
  const float* a1   = (const float*)d_in[5];
  const float* sreq = (const float*)d_in[6];
  const float* a2   = (const float*)d_in[7];
  float* out = (float*)d_out;

  const int M = 4 * 4096;                       // 16384 tokens
  const size_t WN = (size_t)H_DIM * D_DIM;      // 6,553,600 weights each
  constexpr int BM = 128, BN = 128;

  int8_t* w1p  = (int8_t*)d_ws;
  int8_t* w2p  = w1p + WN;
  int8_t* base = w2p + WN;

  // chunk M (multiple of 128) so packed-x chunk + q chunk fit in workspace
  size_t avail = ws_size > 2 * WN ? ws_size - 2 * WN : 0;
  size_t rows = avail / (size_t)(D_DIM + H_DIM);
  int Mc = (int)((rows / BM) * BM);
  if (Mc > M) Mc = M;
  if (Mc < BM) Mc = BM;

  // both weight packs in one launch
  k_packw<<<(int)(2 * WN / 4096), 256, 0, stream>>>(w132, w232, w1p, (long)WN);

  for (int m0 = 0; m0 < M; m0 += Mc) {
    const int mc = (M - m0 < Mc) ? (M - m0) : Mc;
    int8_t* xp = base;
    int8_t* q  = base + (size_t)Mc * D_DIM;
    const size_t nx = (size_t)mc * D_DIM;
    const int mt = mc / BM;
    k_pack<<<(int)(nx / 4096), 256, 0, stream>>>(x32 + (size_t)m0 * D_DIM, xp, (long)nx);
    k_gemm<D_DIM, H_DIM, true><<<mt * (H_DIM / BN), 256, 0, stream>>>(
        xp, w1p, b1, a1, sreq, q, mt);
    k_gemm<H_DIM, D_DIM, false><<<mt * (D_DIM / BN), 256, 0, stream>>>(
        q, w2p, b2, a2, nullptr, out + (size_t)m0 * D_DIM, mt);
  }
}

// Round 6
// 314.877 us; speedup vs baseline: 1.2907x; 1.0589x over previous
//
#include <hip/hip_runtime.h>
#include <stdint.h>
#include <math.h>

typedef __attribute__((ext_vector_type(4))) int i32x4;
typedef __attribute__((ext_vector_type(16))) int i32x16;
typedef __attribute__((ext_vector_type(4))) float f32x4;

constexpr int D_DIM = 1280;   // embedding dim (lin1 K, lin2 N)
constexpr int H_DIM = 5120;   // mlp dim      (lin1 N, lin2 K)

__device__ __forceinline__ void gload_lds16(const void* g, void* l) {
  __builtin_amdgcn_global_load_lds(
      (const __attribute__((address_space(1))) void*)g,
      (__attribute__((address_space(3))) void*)l,
      16, 0, 0);
}

// branchless erf, Abramowitz-Stegun 7.1.26, |eps| <= 1.5e-7
__device__ __forceinline__ float gelu_fast(float h) {
  const float x = h * 0.70710678118f;
  const float ax = fabsf(x);
  const float t = __frcp_rn(__builtin_fmaf(0.3275911f, ax, 1.0f));
  float p = __builtin_fmaf(1.061405429f, t, -1.453152027f);
  p = __builtin_fmaf(p, t, 1.421413741f);
  p = __builtin_fmaf(p, t, -0.284496736f);
  p = __builtin_fmaf(p, t, 0.254829592f);
  p *= t;
  const float e = __expf(-x * x);
  const float erf_ax = __builtin_fmaf(-p, e, 1.0f);
  const float erf_x = copysignf(erf_ax, x);
  return 0.5f * h * (1.0f + erf_x);
}

// ---- pack int32 (sign-extended int8) -> int8; two sources fused -------------
__global__ void __launch_bounds__(256) k_packw(const int* __restrict__ s1,
                                               const int* __restrict__ s2,
                                               int8_t* __restrict__ out,
                                               long wn) {
  long i = ((long)blockIdx.x * 256 + threadIdx.x) * 16;
  const int* p = (i < wn) ? (s1 + i) : (s2 + (i - wn));
  i32x4 a = *(const i32x4*)(p);
  i32x4 b = *(const i32x4*)(p + 4);
  i32x4 c = *(const i32x4*)(p + 8);
  i32x4 d = *(const i32x4*)(p + 12);
  i32x4 r;
  r.x = (a.x & 255) | ((a.y & 255) << 8) | ((a.z & 255) << 16) | (a.w << 24);
  r.y = (b.x & 255) | ((b.y & 255) << 8) | ((b.z & 255) << 16) | (b.w << 24);
  r.z = (c.x & 255) | ((c.y & 255) << 8) | ((c.z & 255) << 16) | (c.w << 24);
  r.w = (d.x & 255) | ((d.y & 255) << 8) | ((d.z & 255) << 16) | (d.w << 24);
  *(i32x4*)(out + i) = r;
}

__global__ void __launch_bounds__(256) k_pack(const int* __restrict__ in,
                                              int8_t* __restrict__ out,
                                              long n) {
  long i = ((long)blockIdx.x * 256 + threadIdx.x) * 16;
  if (i >= n) return;
  const int* p = in + i;
  i32x4 a = *(const i32x4*)(p);
  i32x4 b = *(const i32x4*)(p + 4);
  i32x4 c = *(const i32x4*)(p + 8);
  i32x4 d = *(const i32x4*)(p + 12);
  i32x4 r;
  r.x = (a.x & 255) | ((a.y & 255) << 8) | ((a.z & 255) << 16) | (a.w << 24);
  r.y = (b.x & 255) | ((b.y & 255) << 8) | ((b.z & 255) << 16) | (b.w << 24);
  r.z = (c.x & 255) | ((c.y & 255) << 8) | ((c.z & 255) << 16) | (c.w << 24);
  r.w = (d.x & 255) | ((d.y & 255) << 8) | ((d.z & 255) << 16) | (d.w << 24);
  *(i32x4*)(out + i) = r;
}

// ---- fused int8 GEMM: 128x128 tile, BK=128, 32x32x32 MFMA, static dbuf ------
// A [Mt*128, KDIM] i8 row-major; B [NDIM, KDIM] i8 row-major (NT GEMM).
// GELU=true : transposed acc (mfma(b,a)); requant -> packed dwords -> swizzled
//             LDS tile -> coalesced dwordx4 global stores. int8 out [ld NDIM].
// GELU=false: fp32 out = acc*s1 + bias.
template <int KDIM, int NDIM, bool GELU>
__global__ void __launch_bounds__(256, 2)
k_gemm(const int8_t* __restrict__ A, const int8_t* __restrict__ B,
       const float* __restrict__ bias, const float* __restrict__ ps1,
       const float* __restrict__ ps2, void* __restrict__ Cout, int Mtiles) {
  constexpr int BM = 128, BN = 128, BKB = 128;
  constexpr int NT = KDIM / BKB;   // 10 (lin1) / 40 (lin2); both even
  constexpr int BNC = NDIM / BN;   // 40 / 10
  constexpr int G = BNC * 4;

  // layout: [A buf0 16K][A buf1 16K][B buf0 16K][B buf1 16K]
  __shared__ __align__(16) int8_t smem[4 * 16384];

  // ---- block mapping: bijective XCD chunk + 4-row grouping (r4-verified) ----
  const int nwg = Mtiles * BNC;
  int bm, bn;
  {
    const int bid = blockIdx.x;
    const int q = nwg >> 3, r = nwg & 7, x = bid & 7, l = bid >> 3;
    const int swz = (x < r ? x * (q + 1) : r * (q + 1) + (x - r) * q) + l;
    if ((Mtiles & 3) == 0) {
      const int g = swz / G, rr = swz % G;
      bn = rr >> 2;
      bm = g * 4 + (rr & 3);
    } else {
      bn = swz % BNC;
      bm = swz / BNC;
    }
  }

  const int tid = threadIdx.x;
  const int lane = tid & 63, wid = tid >> 6;
  const int wr = wid >> 1, wc = wid & 1;  // 2x2 waves, 64x64 out each

  // ---- staging: linear LDS dest, inverse-swizzled global source -------------
  const int srow = tid >> 3;                       // 0..31
  const int soff = (((tid & 7) ^ (srow & 7)) << 4);
  const int8_t* Ath = A + (size_t)(bm * BM + srow) * KDIM + soff;
  const int8_t* Bth = B + (size_t)(bn * BN + srow) * KDIM + soff;
  const int dT = tid * 16;

  auto STAGE = [&](int boff, const int8_t* ga, const int8_t* gb) {
#pragma unroll
    for (int p = 0; p < 4; ++p)
      gload_lds16(ga + (size_t)(p * 32) * KDIM, smem + boff + dT + p * 4096);
#pragma unroll
    for (int p = 0; p < 4; ++p)
      gload_lds16(gb + (size_t)(p * 32) * KDIM,
                  smem + 32768 + boff + dT + p * 4096);
  };

  // ---- fragment addresses (32x32x32: row = lane&31, k = (lane>>5)*16+b) -----
  const int r32 = lane & 31, hi5 = lane >> 5;
  const int fsw = (lane & 7) << 4;   // row&7 == lane&7 (row offsets are mult-8)
  const int kq = hi5 << 4;
  const int8_t* aP[4];
  const int8_t* bP[4];
#pragma unroll
  for (int ks = 0; ks < 4; ++ks) {
    const int koff = (ks * 32 + kq) ^ fsw;
    aP[ks] = smem + (wr * 64 + r32) * BKB + koff;
    bP[ks] = smem + 32768 + (wc * 64 + r32) * BKB + koff;
  }

  i32x16 acc[2][2] = {};

  auto COMPUTE = [&](int boff) {
#pragma unroll
    for (int ks = 0; ks < 4; ++ks) {
      i32x4 a0 = *(const i32x4*)(aP[ks] + boff);
      i32x4 a1 = *(const i32x4*)(aP[ks] + boff + 4096);
      i32x4 b0 = *(const i32x4*)(bP[ks] + boff);
      i32x4 b1 = *(const i32x4*)(bP[ks] + boff + 4096);
      if constexpr (GELU) {  // transposed: acc[n][m], D-row = h, D-col = token
        acc[0][0] = __builtin_amdgcn_mfma_i32_32x32x32_i8(b0, a0, acc[0][0], 0, 0, 0);
        acc[0][1] = __builtin_amdgcn_mfma_i32_32x32x32_i8(b0, a1, acc[0][1], 0, 0, 0);
        acc[1][0] = __builtin_amdgcn_mfma_i32_32x32x32_i8(b1, a0, acc[1][0], 0, 0, 0);
        acc[1][1] = __builtin_amdgcn_mfma_i32_32x32x32_i8(b1, a1, acc[1][1], 0, 0, 0);
      } else {               // normal: acc[m][n], D-row = token, D-col = d
        acc[0][0] = __builtin_amdgcn_mfma_i32_32x32x32_i8(a0, b0, acc[0][0], 0, 0, 0);
        acc[0][1] = __builtin_amdgcn_mfma_i32_32x32x32_i8(a0, b1, acc[0][1], 0, 0, 0);
        acc[1][0] = __builtin_amdgcn_mfma_i32_32x32x32_i8(a1, b0, acc[1][0], 0, 0, 0);
        acc[1][1] = __builtin_amdgcn_mfma_i32_32x32x32_i8(a1, b1, acc[1][1], 0, 0, 0);
      }
    }
  };

  // ---- main loop: unroll-2, static buffer offsets, 1 barrier per tile -------
  STAGE(0, Ath, Bth);
  __syncthreads();
  const int8_t* gA = Ath + BKB;
  const int8_t* gB = Bth + BKB;
#pragma unroll 1
  for (int t = 0; t < NT; t += 2) {
    STAGE(16384, gA, gB);          // tile t+1 -> buf1
    COMPUTE(0);                    // tile t from buf0
    __syncthreads();               // drains vmcnt+lgkm: buf1 ready, buf0 free
    if (t + 2 < NT) STAGE(0, gA + BKB, gB + BKB);  // tile t+2 -> buf0
    COMPUTE(16384);                // tile t+1 from buf1
    __syncthreads();
    gA += 2 * BKB;
    gB += 2 * BKB;
  }

  // ---- epilogue -------------------------------------------------------------
  // 32x32 C/D layout: col = lane&31, row = (reg&3) + 8*(reg>>2) + 4*(lane>>5)
  if constexpr (GELU) {
    const float s1 = *ps1;
    const float rs = 1.0f / (*ps2);
    int8_t* Q = (int8_t*)Cout;
    int8_t* lb = smem;  // 16 KB token-major q tile, 16B-slot XOR swizzle
#pragma unroll
    for (int n = 0; n < 2; ++n) {
#pragma unroll
      for (int q = 0; q < 4; ++q) {
        const int hl = wc * 64 + n * 32 + q * 8 + hi5 * 4;  // local h base
        const f32x4 bv = *(const f32x4*)(bias + bn * BN + hl);
#pragma unroll
        for (int m = 0; m < 2; ++m) {
          uint32_t pk = 0;
#pragma unroll
          for (int rr = 0; rr < 4; ++rr) {
            const float h = __builtin_fmaf((float)acc[n][m][q * 4 + rr], s1, bv[rr]);
            float qf = rintf(gelu_fast(h) * rs);
            qf = fminf(127.0f, fmaxf(-128.0f, qf));
            pk |= ((uint32_t)((int)qf & 255)) << (rr * 8);
          }
          const int row = wr * 64 + m * 32 + r32;  // local token
          const int ad = row * 128 + ((((hl >> 4) ^ (row & 7)) << 4)) + (hl & 12);
          *(uint32_t*)(lb + ad) = pk;
        }
      }
    }
    __syncthreads();
    // readback: wave-instr = 8 full 128B rows, coalesced dwordx4 stores
#pragma unroll
    for (int it = 0; it < 4; ++it) {
      const int row = wid * 32 + it * 8 + (lane >> 3);
      const int sl = lane & 7;
      i32x4 v = *(const i32x4*)(lb + row * 128 + ((sl ^ (row & 7)) << 4));
      *(i32x4*)(Q + (size_t)(bm * BM + row) * NDIM + bn * BN + sl * 16) = v;
    }
  } else {
    const float s1 = *ps1;
    float* O = (float*)Cout;
    const int colb = bn * BN + wc * 64 + r32;
#pragma unroll
    for (int n = 0; n < 2; ++n) {
      const int col = colb + n * 32;
      const float bv = bias[col];
#pragma unroll
      for (int m = 0; m < 2; ++m) {
        const int rowb = bm * BM + wr * 64 + m * 32 + hi5 * 4;
#pragma unroll
        for (int q = 0; q < 4; ++q)
#pragma unroll
          for (int rr = 0; rr < 4; ++rr) {
            const int row = rowb + q * 8 + rr;
            O[(size_t)row * NDIM + col] =
                __builtin_fmaf((float)acc[m][n][q * 4 + rr], s1, bv);
          }
      }
    }
  }
}

extern "C" void kernel_launch(void* const* d_in, const int* in_sizes, int n_in,
                              void* d_out, int out_size, void* d_ws, size_t ws_size,
                              hipStream_t stream) {
  (void)in_sizes; (void)n_in; (void)out_size;
  const int*   x32  = (const int*)d_in[0];
  const int*   w132 = (const int*)d_in[1];
  const float* b1   = (const float*)d_in[2];
  const int*   w232 = (const int*)d_in[3];
  const float* b2   = (const float*)d_in[4];
  const float* a1   = (const float*)d_in[5];
  const float* sreq = (const float*)d_in[6];
  const float* a2   = (const float*)d_in[7];
  float* out = (float*)d_out;

  const int M = 4 * 4096;                       // 16384 tokens
  const size_t WN = (size_t)H_DIM * D_DIM;      // 6,553,600 weights each
  constexpr int BM = 128, BN = 128;

  int8_t* w1p  = (int8_t*)d_ws;
  int8_t* w2p  = w1p + WN;
  int8_t* base = w2p + WN;

  // chunk M (multiple of 128) so packed-x chunk + q chunk fit in workspace
  size_t avail = ws_size > 2 * WN ? ws_size - 2 * WN : 0;
  size_t rows = avail / (size_t)(D_DIM + H_DIM);
  int Mc = (int)((rows / BM) * BM);
  if (Mc > M) Mc = M;
  if (Mc < BM) Mc = BM;

  k_packw<<<(int)(2 * WN / 4096), 256, 0, stream>>>(w132, w232, w1p, (long)WN);

  for (int m0 = 0; m0 < M; m0 += Mc) {
    const int mc = (M - m0 < Mc) ? (M - m0) : Mc;
    int8_t* xp = base;
    int8_t* q  = base + (size_t)Mc * D_DIM;
    const size_t nx = (size_t)mc * D_DIM;
    const int mt = mc / BM;
    k_pack<<<(int)(nx / 4096), 256, 0, stream>>>(x32 + (size_t)m0 * D_DIM, xp, (long)nx);
    k_gemm<D_DIM, H_DIM, true><<<mt * (H_DIM / BN), 256, 0, stream>>>(
        xp, w1p, b1, a1, sreq, q, mt);
    k_gemm<H_DIM, D_DIM, false><<<mt * (D_DIM / BN), 256, 0, stream>>>(
        q, w2p, b2, a2, nullptr, out + (size_t)m0 * D_DIM, mt);
  }
}